// Round 1
// baseline (164.035 us; speedup 1.0000x reference)
//
#include <hip/hip_runtime.h>
#include <hip/hip_bf16.h>

// GCNConv: out[i] = sum_{e: row[e]=i} dis[row]*dis[col]*xl[col] + dis[i]^2*xl[i]
// N=50000, E=1.6M, D=128, fp32 in/out.
//
// R15 -> R16 (k_reduce rewrite, 51.5us measured -> target ~30us):
//  - Premultiply: y[j] = dis[j]*xl[j] folded into k_split epilogue (in-place on
//    xlb). out[i] = dis[i]*(y[i] + sum y[col]). Kills per-edge norm shfl + the
//    divergent dis[c] gather in k_reduce; self-loop becomes "+y[i]".
//  - k_reduce gathers 8B/lane (ushort4, 32 lanes/row, 2 edges per wave-load):
//    0.5 loads + 0.5 bpermutes per edge (was 1 + 2). Halves merged via
//    __shfl_xor(.,32) at the end.
//  - Ping-pong A/B groups (8 pairs each): next group's shfl+loads issue before
//    current group is consumed -> counted vmcnt waits, ~16 loads in flight.

#define D     128
#define TILE  8192
#define BINB  1024      // k_binjoint block size
#define RPB   128       // rows per bucket
#define MAXB  512       // bucket id fits 9 bits
#define SPLIT_CAP 8192  // LDS sort capacity (= CAP for N=50000/E=1.6M)

typedef short  bf16x8 __attribute__((ext_vector_type(8)));
typedef float  f32x4  __attribute__((ext_vector_type(4)));
typedef unsigned short us4 __attribute__((ext_vector_type(4)));
typedef unsigned short us8 __attribute__((ext_vector_type(8)));

static __device__ __forceinline__ unsigned short f2bf(float f) {
    unsigned u = __float_as_uint(f);
    u = (u + 0x7FFFu + ((u >> 16) & 1u)) >> 16;   // RNE
    return (unsigned short)u;
}
static __device__ __forceinline__ float bf2f(unsigned short s) {
    return __uint_as_float(((unsigned)s) << 16);
}

// --- init: bcur[b]=b*CAP, bcurC[b]=b*CAPC, wtb = bf16(W^T) ---------------
__global__ __launch_bounds__(256) void k_prep(const float* __restrict__ W,
                                              unsigned short* __restrict__ wtb,
                                              int* __restrict__ bcur,
                                              int* __restrict__ bcurC,
                                              int NB, int CAP, int CAPC) {
    int i = blockIdx.x * 256 + threadIdx.x;
    if (i < NB) { bcur[i] = i * CAP; bcurC[i] = i * CAPC; }
    if (i < D * D) {
        int n = i >> 7, k = i & 127;
        wtb[n * 128 + k] = f2bf(W[k * 128 + n]);
    }
}

// --- fused: blocks <NT bin edges; blocks >=NT do MFMA gemm ---------------
__global__ __launch_bounds__(1024) void k_binjoint(
        const int* __restrict__ rows, const int* __restrict__ cols,
        int* __restrict__ bcur, int* __restrict__ bcurC,
        unsigned* __restrict__ ebuf, unsigned char* __restrict__ cebuf,
        const float* __restrict__ x, const unsigned short* __restrict__ wtb,
        const float* __restrict__ bia, unsigned short* __restrict__ xlb,
        int E, int N, int NB, int CAP, int CAPC, int NT) {
    __shared__ __align__(16) unsigned char smem[65536];
    const int t = threadIdx.x;

    if ((int)blockIdx.x >= NT) {
        // ---------------- gemm path: 64x128 tile, waves 0-3 compute ------
        unsigned short (*wt)[136] = (unsigned short (*)[136])smem;            // 34816 B
        unsigned short (*xs)[136] = (unsigned short (*)[136])(smem + 34816);  // 17408 B
        const int row0 = ((int)blockIdx.x - NT) * 64;
        #pragma unroll
        for (int i = 0; i < 2; ++i) {         // W^T: 2048 ushort8 chunks
            int j = i * 1024 + t;
            int n = j >> 4, k8 = j & 15;
            us8 v = *(const us8*)&wtb[j * 8];
            *(us8*)&wt[n][k8 * 8] = v;
        }
        #pragma unroll
        for (int i = 0; i < 2; ++i) {         // x: 2048 float4 -> ushort4
            int j = i * 1024 + t;
            int r = j >> 5, c4 = j & 31;
            int gr = row0 + r;
            us4 o = (us4){0, 0, 0, 0};
            if (gr < N) {
                float4 v = *(const float4*)&x[(size_t)gr * D + c4 * 4];
                o = (us4){f2bf(v.x), f2bf(v.y), f2bf(v.z), f2bf(v.w)};
            }
            *(us4*)&xs[r][c4 * 4] = o;
        }
        __syncthreads();
        if (t < 256) {
            const int w  = t >> 6, l = t & 63;
            const int m0 = w * 16;
            const int lm = l & 15, lq = l >> 4;
            f32x4 acc[8];
            #pragma unroll
            for (int nt = 0; nt < 8; ++nt) acc[nt] = (f32x4){0.f, 0.f, 0.f, 0.f};
            #pragma unroll
            for (int kk = 0; kk < 4; ++kk) {
                const int kof = kk * 32 + lq * 8;
                bf16x8 a = *(const bf16x8*)&xs[m0 + lm][kof];
                #pragma unroll
                for (int nt = 0; nt < 8; ++nt) {
                    bf16x8 bb = *(const bf16x8*)&wt[nt * 16 + lm][kof];
                    acc[nt] = __builtin_amdgcn_mfma_f32_16x16x32_bf16(a, bb, acc[nt], 0, 0, 0);
                }
            }
            #pragma unroll
            for (int nt = 0; nt < 8; ++nt) {
                const int col = nt * 16 + lm;
                const float bc = bia[col];
                #pragma unroll
                for (int r = 0; r < 4; ++r) {
                    int grow = row0 + m0 + lq * 4 + r;
                    if (grow < N) xlb[(size_t)grow * D + col] = f2bf(acc[nt][r] + bc);
                }
            }
        }
        return;
    }

    // ---------------- bin path: in-LDS dual sort, coalesced writes -------
    unsigned*       sorted  = (unsigned*)smem;                  // 32 KB
    unsigned short* sortedC = (unsigned short*)(smem + 32768);  // 16 KB
    int* lcnt   = (int*)(smem + 49152);
    int* lbase  = lcnt + 512;
    int* excl   = lcnt + 1024;
    int* cur    = lcnt + 1536;
    int* lcntC  = lcnt + 2048;
    int* lbaseC = lcnt + 2560;
    int* exclC  = lcnt + 3072;
    int* curC   = lcnt + 3584;                                  // ends at 64 KB

    const int base = blockIdx.x * TILE;
    int m = E - base; if (m > TILE) m = TILE;

    unsigned p[TILE / BINB];
    unsigned short q[TILE / BINB];
    #pragma unroll
    for (int it = 0; it < TILE / BINB; ++it) {
        int i = it * BINB + t;
        if (i < m) {
            unsigned r = (unsigned)rows[base + i];
            unsigned c = (unsigned)cols[base + i];
            p[it] = c | ((r & 127u) << 16) | ((r >> 7) << 23);
            q[it] = (unsigned short)c;           // bucket = c>>7, local = c&127
        }
    }
    if (t < 512) { lcnt[t] = 0; lcntC[t] = 0; }
    __syncthreads();
    #pragma unroll
    for (int it = 0; it < TILE / BINB; ++it) {
        int i = it * BINB + t;
        if (i < m) {
            atomicAdd(&lcnt[p[it] >> 23], 1);
            atomicAdd(&lcntC[q[it] >> 7], 1);
        }
    }
    __syncthreads();
    // wave 0: row scan (8 keys/lane); wave 1: col scan; write excl AND cur
    if (t < 64) {
        int k0 = t * 8, v[8], s = 0;
        #pragma unroll
        for (int u = 0; u < 8; ++u) { v[u] = lcnt[k0 + u]; s += v[u]; }
        int inc = s;
        #pragma unroll
        for (int off = 1; off < 64; off <<= 1) { int o = __shfl_up(inc, off); if (t >= off) inc += o; }
        int run = inc - s;
        #pragma unroll
        for (int u = 0; u < 8; ++u) { excl[k0 + u] = run; cur[k0 + u] = run; run += v[u]; }
    } else if (t < 128) {
        int l = t - 64, k0 = l * 8, v[8], s = 0;
        #pragma unroll
        for (int u = 0; u < 8; ++u) { v[u] = lcntC[k0 + u]; s += v[u]; }
        int inc = s;
        #pragma unroll
        for (int off = 1; off < 64; off <<= 1) { int o = __shfl_up(inc, off); if (l >= off) inc += o; }
        int run = inc - s;
        #pragma unroll
        for (int u = 0; u < 8; ++u) { exclC[k0 + u] = run; curC[k0 + u] = run; run += v[u]; }
    }
    for (int b = t; b < NB; b += BINB) {     // reserve global regions
        int c = lcnt[b];
        lbase[b] = c ? atomicAdd(&bcur[b], c) : 0;
        int cc = lcntC[b];
        lbaseC[b] = cc ? atomicAdd(&bcurC[b], cc) : 0;
    }
    __syncthreads();
    #pragma unroll
    for (int it = 0; it < TILE / BINB; ++it) {  // scatter into LDS (random: free)
        int i = it * BINB + t;
        if (i < m) {
            int pos  = atomicAdd(&cur[p[it] >> 23], 1);
            sorted[pos] = p[it];
            int posC = atomicAdd(&curC[q[it] >> 7], 1);
            sortedC[posC] = q[it];
        }
    }
    __syncthreads();
    #pragma unroll
    for (int it = 0; it < TILE / BINB; ++it) {  // positional coalesced writes
        int i = it * BINB + t;
        if (i < m) {
            unsigned pp = sorted[i];
            int bk = pp >> 23;
            int g  = lbase[bk] + i - excl[bk];
            if (g < (bk + 1) * CAP) ebuf[g] = pp & 0x7FFFFFu;   // col | rl<<16
            unsigned short qq = sortedC[i];
            int bc = qq >> 7;
            int gc = lbaseC[bc] + i - exclC[bc];
            if (gc < (bc + 1) * CAPC) cebuf[gc] = (unsigned char)(qq & 127u);
        }
    }
}

// --- split (row counting sort -> ecol/begN/endN) + degree/dis + premul ---
__global__ __launch_bounds__(1024) void k_split(const int* __restrict__ bcur,
                                                const int* __restrict__ bcurC,
                                                const unsigned* __restrict__ ebuf,
                                                const unsigned char* __restrict__ cebuf,
                                                unsigned short* __restrict__ ecol,
                                                int* __restrict__ begN,
                                                int* __restrict__ endN,
                                                float* __restrict__ dis,
                                                unsigned short* __restrict__ xlb,
                                                int N, int CAP, int CAPC) {
    __shared__ unsigned short sorted[SPLIT_CAP];    // 16 KB
    __shared__ int cnt[RPB];
    __shared__ int excl[RPB];
    __shared__ int cur[RPB];
    __shared__ int cntD[RPB];
    __shared__ float sdis[RPB];
    const int b = blockIdx.x, t = threadIdx.x;
    const int base = b * CAP;
    int m = bcur[b] - base; if (m > CAP) m = CAP;
    const int baseC = b * CAPC;
    int mD = bcurC[b] - baseC; if (mD > CAPC) mD = CAPC;
    if (t < RPB) { cnt[t] = 0; cntD[t] = 0; }
    __syncthreads();
    // degree hist (col bucket b) — word-packed cebuf reads
    const unsigned* cw = (const unsigned*)(cebuf + baseC);   // base 4-aligned
    int nw = mD >> 2;
    for (int i = t; i < nw; i += 1024) {
        unsigned u = cw[i];
        atomicAdd(&cntD[u & 255u], 1);
        atomicAdd(&cntD[(u >> 8) & 255u], 1);
        atomicAdd(&cntD[(u >> 16) & 255u], 1);
        atomicAdd(&cntD[u >> 24], 1);
    }
    if (t < (mD & 3)) atomicAdd(&cntD[cebuf[baseC + nw * 4 + t]], 1);
    // row-key counting
    for (int i = t; i < m; i += 1024)
        atomicAdd(&cnt[(ebuf[base + i] >> 16) & 127], 1);
    __syncthreads();
    const int row0 = b * RPB;
    if (t < RPB) {
        float dv = rsqrtf((float)(cntD[t] + 1));
        sdis[t] = dv;
        if (row0 + t < N) dis[row0 + t] = dv;
    }
    if (t < 64) {                                   // wave scan of 128 keys
        int v0 = cnt[2 * t], v1 = cnt[2 * t + 1];
        int s = v0 + v1, inc = s;
        #pragma unroll
        for (int off = 1; off < 64; off <<= 1) { int o = __shfl_up(inc, off); if (t >= off) inc += o; }
        int ex = inc - s;
        excl[2 * t] = ex;          cur[2 * t] = ex;
        excl[2 * t + 1] = ex + v0; cur[2 * t + 1] = ex + v0;
    }
    __syncthreads();
    if (t < RPB && row0 + t < N) {
        begN[row0 + t] = base + excl[t];
        endN[row0 + t] = base + excl[t] + cnt[t];
    }
    for (int i = t; i < m; i += 1024) {
        unsigned p = ebuf[base + i];
        int pos = atomicAdd(&cur[(p >> 16) & 127], 1);
        sorted[pos] = (unsigned short)(p & 0xFFFFu);   // random scatter in LDS
    }
    // premultiply this block's 128 xlb rows by dis (y = dis*xl), in place.
    // 128 rows x 16 ushort8 = 2048 chunks over 1024 threads. Overlaps the
    // LDS scatter's lgkm latency with global traffic.
    #pragma unroll
    for (int k = 0; k < 2; ++k) {
        int j = k * 1024 + t;
        int r = j >> 4, e8 = j & 15;
        int gr = row0 + r;
        if (gr < N) {
            unsigned short* px = &xlb[(size_t)gr * D + e8 * 8];
            us8 v = *(const us8*)px;
            float dv = sdis[r];
            us8 o;
            #pragma unroll
            for (int qq = 0; qq < 8; ++qq) o[qq] = f2bf(dv * bf2f(v[qq]));
            *(us8*)px = o;
        }
    }
    __syncthreads();
    for (int i = t; i < m; i += 1024)
        ecol[base + i] = sorted[i];                     // linear coalesced write
}

// --- wave-per-node gather-reduce: 2 edges/load, ping-pong prefetch -------
// xlb holds y = dis*xl. out[i] = dis[i] * (y[i] + sum_{c in N(i)} y[c]).
__global__ __launch_bounds__(256) void k_reduce(const int* __restrict__ begN,
                                                const int* __restrict__ endN,
                                                const unsigned short* __restrict__ ecol,
                                                const float* __restrict__ dis,
                                                const unsigned short* __restrict__ xlb,
                                                float* __restrict__ out, int N) {
    const int wave = threadIdx.x >> 6;
    const int lane = threadIdx.x & 63;
    const int half = lane >> 5;          // which edge of the pair this lane serves
    const int l32  = lane & 31;          // 32 lanes x ushort4 = one 256B row
    const int i = blockIdx.x * 4 + wave;
    if (i >= N) return;

    float a0, a1, a2, a3;
    {   // self loop: y[i]; only half 0 contributes (halves are summed at the end)
        us4 sv = *(const us4*)&xlb[(size_t)i * D + (l32 << 2)];
        float s = (half == 0) ? 1.0f : 0.0f;
        a0 = s * bf2f(sv[0]); a1 = s * bf2f(sv[1]);
        a2 = s * bf2f(sv[2]); a3 = s * bf2f(sv[3]);
    }
    const int beg = begN[i], end = endN[i];

#define FETCH(V, J) do { \
    _Pragma("unroll") \
    for (int u = 0; u < 8; ++u) { \
        int cc = __shfl(c, (J) + 2 * u + half); \
        V[u] = *(const us4*)&xlb[((size_t)cc << 7) + (l32 << 2)]; \
    } } while (0)
#define CFULL(V) do { \
    _Pragma("unroll") \
    for (int u = 0; u < 8; ++u) { \
        a0 += bf2f(V[u][0]); a1 += bf2f(V[u][1]); \
        a2 += bf2f(V[u][2]); a3 += bf2f(V[u][3]); \
    } } while (0)
#define CTAIL(V, J) do { \
    _Pragma("unroll") \
    for (int u = 0; u < 8; ++u) { \
        float w = ((J) + 2 * u + half < m) ? 1.0f : 0.0f; \
        a0 = fmaf(w, bf2f(V[u][0]), a0); a1 = fmaf(w, bf2f(V[u][1]), a1); \
        a2 = fmaf(w, bf2f(V[u][2]), a2); a3 = fmaf(w, bf2f(V[u][3]), a3); \
    } } while (0)

    for (int base = beg; base < end; base += 64) {
        int m = end - base; if (m > 64) m = 64;
        int c = 0;
        if (lane < m) c = ecol[base + lane];   // inactive lanes: row 0 (masked later)
        us4 A[8], B[8];
        int j = 0;
        FETCH(A, 0);                           // group = 8 pairs = 16 edges
        for (; j + 32 <= m; j += 32) {
            FETCH(B, j + 16);                  // issue next before consuming A
            CFULL(A);
            if (j + 32 < m) FETCH(A, j + 32);
            CFULL(B);
        }
        int rem = m - j;                       // 0 < rem < 32 => A fetched at j
        if (rem > 0) {
            if (rem > 16) { FETCH(B, j + 16); CFULL(A); CTAIL(B, j + 16); }
            else          { CTAIL(A, j); }
        }
    }
#undef FETCH
#undef CFULL
#undef CTAIL

    // merge the two halves (each covered alternating edges of same columns)
    a0 += __shfl_xor(a0, 32);
    a1 += __shfl_xor(a1, 32);
    a2 += __shfl_xor(a2, 32);
    a3 += __shfl_xor(a3, 32);
    if (half == 0) {
        const float di = dis[i];
        *(float4*)&out[(size_t)i * D + (l32 << 2)] =
            make_float4(di * a0, di * a1, di * a2, di * a3);
    }
}

// ======================= fallback (R1 atomic path) =======================
__global__ __launch_bounds__(256) void k_zero(int* __restrict__ p, int n) {
    int i = blockIdx.x * 256 + threadIdx.x;
    if (i < n) p[i] = 0;
}
__global__ __launch_bounds__(256) void k_deg(const int* __restrict__ cols,
                                             int* __restrict__ cntc, int E) {
    int e = blockIdx.x * 256 + threadIdx.x;
    if (e < E) atomicAdd(&cntc[cols[e]], 1);
}
__global__ __launch_bounds__(256) void k_dis(const int* __restrict__ cntc,
                                             float* __restrict__ dis, int N) {
    int i = blockIdx.x * 256 + threadIdx.x;
    if (i < N) dis[i] = rsqrtf((float)(cntc[i] + 1));
}
#define GEMM_R 8
__global__ __launch_bounds__(128) void k_gemmf(const float* __restrict__ x,
                                               const float* __restrict__ W,
                                               const float* __restrict__ b,
                                               float* __restrict__ xl, int N) {
    __shared__ float xs[GEMM_R][D];
    const int c  = threadIdx.x;
    const int r0 = blockIdx.x * GEMM_R;
    #pragma unroll
    for (int r = 0; r < GEMM_R; ++r) {
        int row = r0 + r;
        xs[r][c] = (row < N) ? x[row * D + c] : 0.0f;
    }
    __syncthreads();
    float acc[GEMM_R];
    const float bc = b[c];
    #pragma unroll
    for (int r = 0; r < GEMM_R; ++r) acc[r] = bc;
    for (int k = 0; k < D; k += 4) {
        const float w0 = W[(k + 0) * D + c];
        const float w1 = W[(k + 1) * D + c];
        const float w2 = W[(k + 2) * D + c];
        const float w3 = W[(k + 3) * D + c];
        #pragma unroll
        for (int r = 0; r < GEMM_R; ++r) {
            const float4 xv = *reinterpret_cast<const float4*>(&xs[r][k]);
            acc[r] = fmaf(xv.x, w0, acc[r]);
            acc[r] = fmaf(xv.y, w1, acc[r]);
            acc[r] = fmaf(xv.z, w2, acc[r]);
            acc[r] = fmaf(xv.w, w3, acc[r]);
        }
    }
    #pragma unroll
    for (int r = 0; r < GEMM_R; ++r) {
        int row = r0 + r;
        if (row < N) xl[row * D + c] = acc[r];
    }
}
__global__ __launch_bounds__(256) void k_self(const float* __restrict__ xl,
                                              const float* __restrict__ dis,
                                              float* __restrict__ out, int N) {
    int gid = blockIdx.x * 256 + threadIdx.x;
    int i = gid >> 7;
    if (i < N) {
        float d = dis[i];
        out[gid] = d * d * xl[gid];
    }
}
__global__ __launch_bounds__(256) void k_scatter(const int* __restrict__ rows,
                                                 const int* __restrict__ cols,
                                                 const float* __restrict__ dis,
                                                 const float* __restrict__ xl,
                                                 float* __restrict__ out, int E) {
    long long gid = (long long)blockIdx.x * 256 + threadIdx.x;
    int e    = (int)(gid >> 6);
    int lane = (int)(gid & 63);
    if (e >= E) return;
    const int row = rows[e];
    const int col = cols[e];
    const float nrm = dis[row] * dis[col];
    atomicAdd(&out[row * D + lane],      nrm * xl[col * D + lane]);
    atomicAdd(&out[row * D + 64 + lane], nrm * xl[col * D + 64 + lane]);
}

// ======================= launch ==========================================
extern "C" void kernel_launch(void* const* d_in, const int* in_sizes, int n_in,
                              void* d_out, int out_size, void* d_ws, size_t ws_size,
                              hipStream_t stream) {
    const float* x   = (const float*)d_in[0];
    const int*   ei  = (const int*)d_in[1];
    const float* W   = (const float*)d_in[2];
    const float* b   = (const float*)d_in[3];
    float*       out = (float*)d_out;

    const int N = in_sizes[0] / D;   // 50000
    const int E = in_sizes[1] / 2;   // 1.6M
    const int* rows = ei;
    const int* cols = ei + E;
    const int NB = (N + RPB - 1) / RPB;        // 391
    const int NT = (E + TILE - 1) / TILE;      // 196
    const int GN = (N + 63) / 64;              // 782 gemm blocks
    const int CAP  = (((2 * E) / NB) + 63) / 64 * 64;  // 8192 (uints)
    const int CAPC = CAP;                              // 8192 (bytes)

    // ws layout
    char* p = (char*)d_ws;
    size_t off = 0;
    unsigned short* xlb   = (unsigned short*)(p + off); off += (size_t)N * D * 2;
    unsigned short* wtb   = (unsigned short*)(p + off); off += (size_t)D * D * 2;
    float*          dis   = (float*)(p + off);          off += (size_t)N * 4;
    int*            bcur  = (int*)(p + off);            off += (size_t)MAXB * 4;
    int*            bcurC = (int*)(p + off);            off += (size_t)MAXB * 4;
    int*            begN  = (int*)(p + off);            off += (size_t)N * 4;
    int*            endN  = (int*)(p + off);            off += (size_t)N * 4;
    unsigned*       ebuf  = (unsigned*)(p + off);       off += (size_t)NB * CAP * 4;
    unsigned short* ecol  = (unsigned short*)(p + off); off += (size_t)NB * CAP * 2;
    unsigned char*  cebuf = (unsigned char*)(p + off);  off += (size_t)NB * CAPC;

    const int gN = (N + 255) / 256;
    const int gE = (E + 255) / 256;

    if (N <= 65536 && NB <= MAXB && CAP <= SPLIT_CAP && ws_size >= off) {
        k_prep    <<<(D * D + 255) / 256, 256, 0, stream>>>(W, wtb, bcur, bcurC, NB, CAP, CAPC);
        k_binjoint<<<NT + GN, BINB, 0, stream>>>(rows, cols, bcur, bcurC, ebuf, cebuf,
                                                 x, wtb, b, xlb, E, N, NB, CAP, CAPC, NT);
        k_split   <<<NB, 1024, 0, stream>>>(bcur, bcurC, ebuf, cebuf, ecol, begN, endN, dis, xlb, N, CAP, CAPC);
        k_reduce  <<<(N + 3) / 4, 256, 0, stream>>>(begN, endN, ecol, dis, xlb, out, N);
    } else {
        // fallback: R1 atomic scatter path (fp32 xl)
        char* q = (char*)d_ws;
        float* xl   = (float*)q;
        float* disF = (float*)(q + (size_t)N * D * 4);
        int*   cc   = (int*)(q + (size_t)N * D * 4 + (size_t)N * 4);
        k_zero <<<gN, 256, 0, stream>>>(cc, N);
        k_deg  <<<gE, 256, 0, stream>>>(cols, cc, E);
        k_dis  <<<gN, 256, 0, stream>>>(cc, disF, N);
        k_gemmf<<<(N + GEMM_R - 1) / GEMM_R, 128, 0, stream>>>(x, W, b, xl, N);
        k_self <<<((N * D) + 255) / 256, 256, 0, stream>>>(xl, disF, out, N);
        long long st = (long long)E * 64;
        k_scatter<<<(int)((st + 255) / 256), 256, 0, stream>>>(rows, cols, disF, xl, out, E);
    }
}